// Round 2
// baseline (1624.569 us; speedup 1.0000x reference)
//
#include <hip/hip_runtime.h>
#include <hip/hip_cooperative_groups.h>

namespace cg = cooperative_groups;

#define T_STEPS 8192
#define SIT     64
#define SS      256
#define S2      512
#define NPL     32000
#define NEV     (2*T_STEPS)
#define MAXLEV  255
#define RELAX   48
#define BQ      16   // steps per block in main kernel

__device__ __forceinline__ float sigmoidf_(float x) {
    return 1.0f / (1.0f + expf(-x));
}

// ---------------- preprocessing kernels ----------------

__global__ void k_zero(int* cnt) {
    int i = blockIdx.x * blockDim.x + threadIdx.x;
    if (i < NPL) cnt[i] = 0;
}

__global__ void k_count(const int* __restrict__ b, const int* __restrict__ p, int* cnt) {
    int e = blockIdx.x * blockDim.x + threadIdx.x;
    if (e < NEV) {
        int v = (e & 1) ? p[e >> 1] : b[e >> 1];
        atomicAdd(&cnt[v], 1);
    }
}

__global__ __launch_bounds__(1024) void k_scan(const int* __restrict__ cnt, int* bas, int* cur) {
    __shared__ int partial[1024];
    int tid = threadIdx.x;
    int start = tid * 32;
    int end = start + 32; if (end > NPL) end = NPL;
    int s = 0;
    for (int i = start; i < end; ++i) s += cnt[i];
    partial[tid] = s;
    __syncthreads();
    for (int off = 1; off < 1024; off <<= 1) {
        int v = partial[tid];
        int add = (tid >= off) ? partial[tid - off] : 0;
        __syncthreads();
        partial[tid] = v + add;
        __syncthreads();
    }
    int acc = (tid == 0) ? 0 : partial[tid - 1];
    for (int i = start; i < end; ++i) {
        bas[i] = acc; cur[i] = acc; acc += cnt[i];
    }
}

__global__ void k_place(const int* __restrict__ b, const int* __restrict__ p, int* cur, int* list) {
    int e = blockIdx.x * blockDim.x + threadIdx.x;
    if (e < NEV) {
        int v = (e & 1) ? p[e >> 1] : b[e >> 1];
        int pos = atomicAdd(&cur[v], 1);
        list[pos] = e;
    }
}

__global__ void k_pred(const int* __restrict__ bas, const int* __restrict__ cnt, int* list, int* pred) {
    int v = blockIdx.x * blockDim.x + threadIdx.x;
    if (v >= NPL) return;
    int s0 = bas[v], c = cnt[v];
    // insertion sort (lists are tiny for random indices)
    for (int i2 = 1; i2 < c; ++i2) {
        int key = list[s0 + i2];
        int j = i2 - 1;
        while (j >= 0 && list[s0 + j] > key) { list[s0 + j + 1] = list[s0 + j]; --j; }
        list[s0 + j + 1] = key;
    }
    int prevS = -1, curS = -1;
    for (int i2 = 0; i2 < c; ++i2) {
        int e = list[s0 + i2];
        int s = e >> 1;
        if (s != curS) { prevS = curS; curS = s; }   // same-step pair shares predecessor
        pred[e] = prevS;
    }
}

__global__ __launch_bounds__(1024) void k_levels(const int* __restrict__ pred,
                                                 int* order, int* levelStart, int* numLevels) {
    __shared__ short p0[T_STEPS], p1[T_STEPS];
    __shared__ unsigned char lev[T_STEPS];
    __shared__ int cnts[MAXLEV + 2];
    __shared__ int maxLev;
    int tid = threadIdx.x;
    for (int t = tid; t < T_STEPS; t += 1024) {
        p0[t] = (short)pred[2 * t];
        p1[t] = (short)pred[2 * t + 1];
        lev[t] = 1;
    }
    for (int l = tid; l < MAXLEV + 2; l += 1024) cnts[l] = 0;
    if (tid == 0) maxLev = 0;
    __syncthreads();
    for (int r = 0; r < RELAX; ++r) {
        for (int t = tid; t < T_STEPS; t += 1024) {
            int a = p0[t], b2 = p1[t];
            int la = (a >= 0) ? (int)lev[a] : 0;
            int lb = (b2 >= 0) ? (int)lev[b2] : 0;
            int nl = 1 + (la > lb ? la : lb);
            if (nl > MAXLEV) nl = MAXLEV;
            if (nl > (int)lev[t]) lev[t] = (unsigned char)nl;  // monotone
        }
        __syncthreads();
    }
    for (int t = tid; t < T_STEPS; t += 1024) {
        atomicAdd(&cnts[lev[t]], 1);
        atomicMax(&maxLev, (int)lev[t]);
    }
    __syncthreads();
    if (tid == 0) {
        int acc = 0;
        levelStart[0] = 0;
        for (int l = 1; l <= maxLev; ++l) {
            int c = cnts[l];
            cnts[l] = acc;           // becomes placement cursor base
            acc += c;
            levelStart[l] = acc;
        }
        *numLevels = maxLev;
    }
    __syncthreads();
    for (int t = tid; t < T_STEPS; t += 1024) {
        int pos = atomicAdd(&cnts[lev[t]], 1);
        order[pos] = t;
    }
}

// transpose U (512x512) into [k/4][512][4] so wave loads are coalesced float4s
__global__ void k_transU(const float* __restrict__ U, float* UtP) {
    int idx = blockIdx.x * blockDim.x + threadIdx.x;
    if (idx < S2 * S2) {
        int i = idx / S2;
        int k = idx % S2;
        UtP[((k >> 2) * S2 + i) * 4 + (k & 3)] = U[idx];
    }
}
// transpose W (512x64) into [k/4][512][4]
__global__ void k_transW(const float* __restrict__ W, float* WtP) {
    int idx = blockIdx.x * blockDim.x + threadIdx.x;
    if (idx < S2 * SIT) {
        int i = idx / SIT;
        int k = idx % SIT;
        WtP[((k >> 2) * S2 + i) * 4 + (k & 3)] = W[idx];
    }
}

__global__ void k_copy(const float4* __restrict__ src, float4* dst, int n4) {
    int i = blockIdx.x * blockDim.x + threadIdx.x;
    if (i < n4) dst[i] = src[i];
}

// ---------------- main cooperative kernel ----------------

__global__ __launch_bounds__(512) void k_main(
    const float* __restrict__ x, const int* __restrict__ bArr, const int* __restrict__ pArr,
    const float* __restrict__ WzT, const float* __restrict__ WrT, const float* __restrict__ WhT,
    const float* __restrict__ UzT, const float* __restrict__ UrT, const float* __restrict__ UhT,
    const float* __restrict__ bz, const float* __restrict__ br, const float* __restrict__ bh,
    float* __restrict__ out, const int* __restrict__ order,
    const int* __restrict__ levelStart, const int* __restrict__ numLevels)
{
    cg::grid_group grid = cg::this_grid();
    __shared__ float Hs[BQ][S2];
    __shared__ float RHs[BQ][S2];
    __shared__ float xs[BQ][SIT];
    __shared__ int tj[BQ];

    const int i = threadIdx.x;            // output row 0..511
    const int nLev = *numLevels;
    const float bzi = bz[i], bri = br[i], bhi = bh[i];
    const float4* Uz4 = (const float4*)UzT;
    const float4* Ur4 = (const float4*)UrT;
    const float4* Uh4 = (const float4*)UhT;
    const float4* Wz4 = (const float4*)WzT;
    const float4* Wr4 = (const float4*)WrT;
    const float4* Wh4 = (const float4*)WhT;

    for (int lvl = 1; lvl <= nLev; ++lvl) {
        const int s0 = levelStart[lvl - 1], s1 = levelStart[lvl];
        const int nBlk = (s1 - s0 + BQ - 1) / BQ;
        for (int blk = blockIdx.x; blk < nBlk; blk += gridDim.x) {
            const int sbase = s0 + blk * BQ;
            const int B = min(BQ, s1 - sbase);
            __syncthreads();   // protect LDS from previous iteration readers
            if (i < BQ) tj[i] = (i < B) ? order[sbase + i] : -1;
            __syncthreads();
            // gather h = concat(table[b], table[p]) for each step, zero-pad tails
            for (int idx = i; idx < BQ * S2; idx += 512) {
                int j = idx >> 9, k = idx & (S2 - 1);
                int t = tj[j];
                float v = 0.0f;
                if (t >= 0) {
                    int row = (k < SS) ? bArr[t] : pArr[t];
                    v = out[row * SS + (k & (SS - 1))];
                }
                Hs[j][k] = v;
            }
            for (int idx = i; idx < BQ * SIT; idx += 512) {
                int j = idx >> 6, k = idx & (SIT - 1);
                int t = tj[j];
                xs[j][k] = (t >= 0) ? x[t * SIT + k] : 0.0f;
            }
            __syncthreads();

            // -------- phase A: z and r pre-activations for row i --------
            float zacc[BQ], racc[BQ];
#pragma unroll
            for (int j = 0; j < BQ; ++j) { zacc[j] = 0.0f; racc[j] = 0.0f; }
            for (int kb = 0; kb < SIT / 4; ++kb) {
                float4 a4 = Wz4[kb * S2 + i];
                float4 b4 = Wr4[kb * S2 + i];
#pragma unroll
                for (int j = 0; j < BQ; ++j) {
                    float4 x4 = *(const float4*)(&xs[j][kb * 4]);
                    zacc[j] += a4.x * x4.x + a4.y * x4.y + a4.z * x4.z + a4.w * x4.w;
                    racc[j] += b4.x * x4.x + b4.y * x4.y + b4.z * x4.z + b4.w * x4.w;
                }
            }
            for (int kb = 0; kb < S2 / 4; ++kb) {
                float4 a4 = Uz4[kb * S2 + i];
                float4 b4 = Ur4[kb * S2 + i];
#pragma unroll
                for (int j = 0; j < BQ; ++j) {
                    float4 h4 = *(const float4*)(&Hs[j][kb * 4]);
                    zacc[j] += a4.x * h4.x + a4.y * h4.y + a4.z * h4.z + a4.w * h4.w;
                    racc[j] += b4.x * h4.x + b4.y * h4.y + b4.z * h4.z + b4.w * h4.w;
                }
            }
            float zv[BQ];
#pragma unroll
            for (int j = 0; j < BQ; ++j) {
                zv[j] = sigmoidf_(zacc[j] + bzi);
                float rv = sigmoidf_(racc[j] - bri);
                RHs[j][i] = rv * Hs[j][i];
            }
            __syncthreads();

            // -------- phase B: m, hn, scatter --------
            float macc[BQ];
#pragma unroll
            for (int j = 0; j < BQ; ++j) macc[j] = 0.0f;
            for (int kb = 0; kb < SIT / 4; ++kb) {
                float4 a4 = Wh4[kb * S2 + i];
#pragma unroll
                for (int j = 0; j < BQ; ++j) {
                    float4 x4 = *(const float4*)(&xs[j][kb * 4]);
                    macc[j] += a4.x * x4.x + a4.y * x4.y + a4.z * x4.z + a4.w * x4.w;
                }
            }
            for (int kb = 0; kb < S2 / 4; ++kb) {
                float4 a4 = Uh4[kb * S2 + i];
#pragma unroll
                for (int j = 0; j < BQ; ++j) {
                    float4 h4 = *(const float4*)(&RHs[j][kb * 4]);
                    macc[j] += a4.x * h4.x + a4.y * h4.y + a4.z * h4.z + a4.w * h4.w;
                }
            }
            for (int j = 0; j < B; ++j) {
                int t = tj[j];
                float mm = tanhf(macc[j] + bhi);
                float h = Hs[j][i];
                float hn = zv[j] * h + (1.0f - zv[j]) * mm;
                int rb = bArr[t], rp = pArr[t];
                int row = (i < SS) ? rb : rp;
                float* addr = out + row * SS + (i & (SS - 1));
                if (rb == rp) atomicAdd(addr, hn - h);  // rare duplicate-within-step
                else *addr = hn;
            }
        }
        grid.sync();
    }
}

// ---------------- host launcher ----------------

extern "C" void kernel_launch(void* const* d_in, const int* in_sizes, int n_in,
                              void* d_out, int out_size, void* d_ws, size_t ws_size,
                              hipStream_t stream) {
    const float* x  = (const float*)d_in[0];
    const int*   b  = (const int*)d_in[1];
    const int*   p  = (const int*)d_in[2];
    const float* Wz = (const float*)d_in[3];
    const float* Wr = (const float*)d_in[4];
    const float* Wh = (const float*)d_in[5];
    const float* Uz = (const float*)d_in[6];
    const float* Ur = (const float*)d_in[7];
    const float* Uh = (const float*)d_in[8];
    const float* bz = (const float*)d_in[9];
    const float* br = (const float*)d_in[10];
    const float* bh = (const float*)d_in[11];
    const float* table0 = (const float*)d_in[12];
    float* out = (float*)d_out;

    // workspace layout (transposed matrices first for 16B alignment)
    float* UzT = (float*)d_ws;
    float* UrT = UzT + S2 * S2;
    float* UhT = UrT + S2 * S2;
    float* WzT = UhT + S2 * S2;
    float* WrT = WzT + S2 * SIT;
    float* WhT = WrT + S2 * SIT;
    int* cnt = (int*)(WhT + S2 * SIT);
    int* cur = cnt + NPL;
    int* bas = cur + NPL;
    int* list = bas + NPL;
    int* pred = list + NEV;
    int* order = pred + NEV;
    int* levelStart = order + T_STEPS;
    int* numLevels = levelStart + 260;

    hipLaunchKernelGGL(k_transU, dim3((S2 * S2 + 255) / 256), dim3(256), 0, stream, Uz, UzT);
    hipLaunchKernelGGL(k_transU, dim3((S2 * S2 + 255) / 256), dim3(256), 0, stream, Ur, UrT);
    hipLaunchKernelGGL(k_transU, dim3((S2 * S2 + 255) / 256), dim3(256), 0, stream, Uh, UhT);
    hipLaunchKernelGGL(k_transW, dim3((S2 * SIT + 255) / 256), dim3(256), 0, stream, Wz, WzT);
    hipLaunchKernelGGL(k_transW, dim3((S2 * SIT + 255) / 256), dim3(256), 0, stream, Wr, WrT);
    hipLaunchKernelGGL(k_transW, dim3((S2 * SIT + 255) / 256), dim3(256), 0, stream, Wh, WhT);

    hipLaunchKernelGGL(k_zero, dim3((NPL + 255) / 256), dim3(256), 0, stream, cnt);
    hipLaunchKernelGGL(k_count, dim3((NEV + 255) / 256), dim3(256), 0, stream, b, p, cnt);
    hipLaunchKernelGGL(k_scan, dim3(1), dim3(1024), 0, stream, cnt, bas, cur);
    hipLaunchKernelGGL(k_place, dim3((NEV + 255) / 256), dim3(256), 0, stream, b, p, cur, list);
    hipLaunchKernelGGL(k_pred, dim3((NPL + 255) / 256), dim3(256), 0, stream, bas, cnt, list, pred);
    hipLaunchKernelGGL(k_levels, dim3(1), dim3(1024), 0, stream, pred, order, levelStart, numLevels);

    int n4 = NPL * SS / 4;
    hipLaunchKernelGGL(k_copy, dim3((n4 + 255) / 256), dim3(256), 0, stream,
                       (const float4*)table0, (float4*)out, n4);

    void* args[] = {
        (void*)&x, (void*)&b, (void*)&p,
        (void*)&WzT, (void*)&WrT, (void*)&WhT,
        (void*)&UzT, (void*)&UrT, (void*)&UhT,
        (void*)&bz, (void*)&br, (void*)&bh,
        (void*)&out, (void*)&order, (void*)&levelStart, (void*)&numLevels
    };
    hipLaunchCooperativeKernel((void*)k_main, dim3(256), dim3(512), args, 0, stream);
}

// Round 4
// 1294.735 us; speedup vs baseline: 1.2548x; 1.2548x over previous
//
#include <hip/hip_runtime.h>
#include <hip/hip_cooperative_groups.h>

namespace cg = cooperative_groups;

#define T_STEPS 8192
#define SIT     64
#define SS      256
#define S2      512
#define NPL     32000
#define NEV     (2*T_STEPS)
#define MAXLEV  255
#define RELAX   48
#define NKB     (S2/4)    // 128 k-blocks for U part
#define WKB     (SIT/4)   // 16 k-blocks for W part

__device__ __forceinline__ float sigmoidf_(float x) {
    return 1.0f / (1.0f + expf(-x));
}
__device__ __forceinline__ float dot4_(float4 a, float4 b) {
    return a.x*b.x + a.y*b.y + a.z*b.z + a.w*b.w;
}

// ---------------- preprocessing kernels ----------------

__global__ void k_zero(int* cnt) {
    int i = blockIdx.x * blockDim.x + threadIdx.x;
    if (i < NPL) cnt[i] = 0;
}

__global__ void k_count(const int* __restrict__ b, const int* __restrict__ p, int* cnt) {
    int e = blockIdx.x * blockDim.x + threadIdx.x;
    if (e < NEV) {
        int v = (e & 1) ? p[e >> 1] : b[e >> 1];
        atomicAdd(&cnt[v], 1);
    }
}

__global__ __launch_bounds__(1024) void k_scan(const int* __restrict__ cnt, int* bas, int* cur) {
    __shared__ int partial[1024];
    int tid = threadIdx.x;
    int start = tid * 32;
    int end = start + 32; if (end > NPL) end = NPL;
    int s = 0;
    for (int i = start; i < end; ++i) s += cnt[i];
    partial[tid] = s;
    __syncthreads();
    for (int off = 1; off < 1024; off <<= 1) {
        int v = partial[tid];
        int add = (tid >= off) ? partial[tid - off] : 0;
        __syncthreads();
        partial[tid] = v + add;
        __syncthreads();
    }
    int acc = (tid == 0) ? 0 : partial[tid - 1];
    for (int i = start; i < end; ++i) {
        bas[i] = acc; cur[i] = acc; acc += cnt[i];
    }
}

__global__ void k_place(const int* __restrict__ b, const int* __restrict__ p, int* cur, int* list) {
    int e = blockIdx.x * blockDim.x + threadIdx.x;
    if (e < NEV) {
        int v = (e & 1) ? p[e >> 1] : b[e >> 1];
        int pos = atomicAdd(&cur[v], 1);
        list[pos] = e;
    }
}

__global__ void k_pred(const int* __restrict__ bas, const int* __restrict__ cnt, int* list, int* pred) {
    int v = blockIdx.x * blockDim.x + threadIdx.x;
    if (v >= NPL) return;
    int s0 = bas[v], c = cnt[v];
    for (int i2 = 1; i2 < c; ++i2) {
        int key = list[s0 + i2];
        int j = i2 - 1;
        while (j >= 0 && list[s0 + j] > key) { list[s0 + j + 1] = list[s0 + j]; --j; }
        list[s0 + j + 1] = key;
    }
    int prevS = -1, curS = -1;
    for (int i2 = 0; i2 < c; ++i2) {
        int e = list[s0 + i2];
        int s = e >> 1;
        if (s != curS) { prevS = curS; curS = s; }
        pred[e] = prevS;
    }
}

__global__ __launch_bounds__(1024) void k_levels(const int* __restrict__ pred,
                                                 int* order, int* levelStart, int* numLevels) {
    __shared__ short p0[T_STEPS], p1[T_STEPS];
    __shared__ unsigned char lev[T_STEPS];
    __shared__ int cnts[MAXLEV + 2];
    __shared__ int maxLev;
    int tid = threadIdx.x;
    for (int t = tid; t < T_STEPS; t += 1024) {
        p0[t] = (short)pred[2 * t];
        p1[t] = (short)pred[2 * t + 1];
        lev[t] = 1;
    }
    for (int l = tid; l < MAXLEV + 2; l += 1024) cnts[l] = 0;
    if (tid == 0) maxLev = 0;
    __syncthreads();
    for (int r = 0; r < RELAX; ++r) {
        for (int t = tid; t < T_STEPS; t += 1024) {
            int a = p0[t], b2 = p1[t];
            int la = (a >= 0) ? (int)lev[a] : 0;
            int lb = (b2 >= 0) ? (int)lev[b2] : 0;
            int nl = 1 + (la > lb ? la : lb);
            if (nl > MAXLEV) nl = MAXLEV;
            if (nl > (int)lev[t]) lev[t] = (unsigned char)nl;
        }
        __syncthreads();
    }
    for (int t = tid; t < T_STEPS; t += 1024) {
        atomicAdd(&cnts[lev[t]], 1);
        atomicMax(&maxLev, (int)lev[t]);
    }
    __syncthreads();
    if (tid == 0) {
        int acc = 0;
        levelStart[0] = 0;
        for (int l = 1; l <= maxLev; ++l) {
            int c = cnts[l];
            cnts[l] = acc;
            acc += c;
            levelStart[l] = acc;
        }
        *numLevels = maxLev;
    }
    __syncthreads();
    for (int t = tid; t < T_STEPS; t += 1024) {
        int pos = atomicAdd(&cnts[lev[t]], 1);
        order[pos] = t;
    }
}

// fused transpose of all 6 matrices into [k/4][512][4] layout
__global__ void k_trans(const float* __restrict__ Uz, const float* __restrict__ Ur,
                        const float* __restrict__ Uh, const float* __restrict__ Wz,
                        const float* __restrict__ Wr, const float* __restrict__ Wh,
                        float* UzT, float* UrT, float* UhT,
                        float* WzT, float* WrT, float* WhT) {
    int y = blockIdx.y;
    int idx = blockIdx.x * blockDim.x + threadIdx.x;
    if (y < 3) {
        const float* S = (y == 0) ? Uz : (y == 1) ? Ur : Uh;
        float*       D = (y == 0) ? UzT : (y == 1) ? UrT : UhT;
        if (idx < S2 * S2) {
            int i2 = idx / S2, k = idx % S2;
            D[((k >> 2) * S2 + i2) * 4 + (k & 3)] = S[idx];
        }
    } else {
        const float* S = (y == 3) ? Wz : (y == 4) ? Wr : Wh;
        float*       D = (y == 3) ? WzT : (y == 4) ? WrT : WhT;
        if (idx < S2 * SIT) {
            int i2 = idx / SIT, k = idx % SIT;
            D[((k >> 2) * S2 + i2) * 4 + (k & 3)] = S[idx];
        }
    }
}

__global__ void k_copy(const float4* __restrict__ src, float4* dst, int n4) {
    int i = blockIdx.x * blockDim.x + threadIdx.x;
    if (i < n4) dst[i] = src[i];
}

// XP = W@x + bias for all steps (non-cooperative; one 16-step tile per block)
__global__ __launch_bounds__(512) void k_xp(
    const float* __restrict__ x,
    const float* __restrict__ WzT, const float* __restrict__ WrT, const float* __restrict__ WhT,
    const float* __restrict__ bz, const float* __restrict__ br, const float* __restrict__ bh,
    float* __restrict__ XPz, float* __restrict__ XPr, float* __restrict__ XPh)
{
    __shared__ float xs[16][SIT];
    const int i = threadIdx.x;
    const int tile = blockIdx.x;              // 0 .. T_STEPS/16-1
    const float4* Wz4 = (const float4*)WzT;
    const float4* Wr4 = (const float4*)WrT;
    const float4* Wh4 = (const float4*)WhT;
    const float bzi = bz[i], bri = br[i], bhi = bh[i];

    for (int idx = i; idx < 16 * SIT; idx += 512) {
        int j = idx >> 6, k = idx & (SIT - 1);
        xs[j][k] = x[(tile * 16 + j) * SIT + k];
    }
    __syncthreads();
    float za[16], ra[16], ha[16];
#pragma unroll
    for (int j = 0; j < 16; ++j) { za[j] = 0.f; ra[j] = 0.f; ha[j] = 0.f; }
    for (int kb = 0; kb < WKB; ++kb) {
        float4 wz = Wz4[kb * S2 + i];
        float4 wr = Wr4[kb * S2 + i];
        float4 wh = Wh4[kb * S2 + i];
#pragma unroll
        for (int j = 0; j < 16; ++j) {
            float4 x4 = *(const float4*)(&xs[j][kb * 4]);
            za[j] += dot4_(wz, x4);
            ra[j] += dot4_(wr, x4);
            ha[j] += dot4_(wh, x4);
        }
    }
#pragma unroll
    for (int j = 0; j < 16; ++j) {
        int t = tile * 16 + j;
        XPz[t * S2 + i] = za[j] + bzi;
        XPr[t * S2 + i] = ra[j] - bri;
        XPh[t * S2 + i] = ha[j] + bhi;
    }
}

// ---------------- main cooperative kernel ----------------
// Round-2-proven inner structure (separate RHs, strided gathers), plus
// XP fast path and template BQ.

template<int BQ>
__device__ __forceinline__ void process_level(
    int s0, int s1, int i, int useXP,
    const float* __restrict__ x,
    const int* __restrict__ bArr, const int* __restrict__ pArr,
    const float4* __restrict__ Wz4, const float4* __restrict__ Wr4, const float4* __restrict__ Wh4,
    const float4* __restrict__ Uz4, const float4* __restrict__ Ur4, const float4* __restrict__ Uh4,
    const float* __restrict__ XPz, const float* __restrict__ XPr, const float* __restrict__ XPh,
    float bzi, float bri, float bhi,
    float* __restrict__ out, const int* __restrict__ order,
    float (*Hs)[S2], float (*RHs)[S2], float (*xs)[SIT], int* tj)
{
    const int nT = (s1 - s0 + BQ - 1) / BQ;
    for (int tile = blockIdx.x; tile < nT; tile += gridDim.x) {
        const int sbase = s0 + tile * BQ;
        const int B = (sbase + BQ <= s1) ? BQ : (s1 - sbase);
        __syncthreads();                       // guard LDS reuse from previous tile
        if (i < BQ) tj[i] = (i < B) ? order[sbase + i] : -1;
        __syncthreads();

        // gather h = concat(table[b], table[p]) per step (strided, round-2 form)
        for (int idx = i; idx < BQ * S2; idx += 512) {
            int j = idx >> 9, k = idx & (S2 - 1);
            int t = tj[j];
            float v = 0.0f;
            if (t >= 0) {
                int row = (k < SS) ? bArr[t] : pArr[t];
                v = out[row * SS + (k & (SS - 1))];
            }
            Hs[j][k] = v;
        }
        if (!useXP) {
            for (int idx = i; idx < BQ * SIT; idx += 512) {
                int j = idx >> 6, k = idx & (SIT - 1);
                int t = tj[j];
                xs[j][k] = (t >= 0) ? x[t * SIT + k] : 0.0f;
            }
        }
        // init accumulators (XP holds W@x with biases folded)
        float zacc[BQ], racc[BQ];
        if (useXP) {
#pragma unroll
            for (int j = 0; j < BQ; ++j) {
                int t = tj[j];
                zacc[j] = (t >= 0) ? XPz[t * S2 + i] : 0.0f;
                racc[j] = (t >= 0) ? XPr[t * S2 + i] : 0.0f;
            }
        } else {
#pragma unroll
            for (int j = 0; j < BQ; ++j) { zacc[j] = 0.0f; racc[j] = 0.0f; }
        }
        __syncthreads();                       // Hs (and xs) ready

        if (!useXP) {
            for (int kb = 0; kb < WKB; ++kb) {
                float4 a4 = Wz4[kb * S2 + i];
                float4 b4 = Wr4[kb * S2 + i];
#pragma unroll
                for (int j = 0; j < BQ; ++j) {
                    float4 x4 = *(const float4*)(&xs[j][kb * 4]);
                    zacc[j] += dot4_(a4, x4);
                    racc[j] += dot4_(b4, x4);
                }
            }
        }
        for (int kb = 0; kb < NKB; ++kb) {
            float4 a4 = Uz4[kb * S2 + i];
            float4 b4 = Ur4[kb * S2 + i];
#pragma unroll
            for (int j = 0; j < BQ; ++j) {
                float4 h4 = *(const float4*)(&Hs[j][kb * 4]);
                zacc[j] += dot4_(a4, h4);
                racc[j] += dot4_(b4, h4);
            }
        }
        float zv[BQ];
#pragma unroll
        for (int j = 0; j < BQ; ++j) {
            zv[j] = sigmoidf_(useXP ? zacc[j] : (zacc[j] + bzi));
            float rv = sigmoidf_(useXP ? racc[j] : (racc[j] - bri));
            RHs[j][i] = rv * Hs[j][i];
        }
        __syncthreads();                       // RHs ready

        // phase B: m
        float macc[BQ];
        if (useXP) {
#pragma unroll
            for (int j = 0; j < BQ; ++j) {
                int t = tj[j];
                macc[j] = (t >= 0) ? XPh[t * S2 + i] : 0.0f;
            }
        } else {
#pragma unroll
            for (int j = 0; j < BQ; ++j) macc[j] = 0.0f;
            for (int kb = 0; kb < WKB; ++kb) {
                float4 a4 = Wh4[kb * S2 + i];
#pragma unroll
                for (int j = 0; j < BQ; ++j) {
                    float4 x4 = *(const float4*)(&xs[j][kb * 4]);
                    macc[j] += dot4_(a4, x4);
                }
            }
        }
        for (int kb = 0; kb < NKB; ++kb) {
            float4 a4 = Uh4[kb * S2 + i];
#pragma unroll
            for (int j = 0; j < BQ; ++j) {
                float4 h4 = *(const float4*)(&RHs[j][kb * 4]);
                macc[j] += dot4_(a4, h4);
            }
        }
        // scatter (round-2 form)
        for (int j = 0; j < B; ++j) {
            int t = tj[j];
            float mm = tanhf(useXP ? macc[j] : (macc[j] + bhi));
            float h = Hs[j][i];
            float hn = zv[j] * h + (1.0f - zv[j]) * mm;
            int rb = bArr[t], rp = pArr[t];
            int row = (i < SS) ? rb : rp;
            float* addr = out + row * SS + (i & (SS - 1));
            if (rb == rp) atomicAdd(addr, hn - h);
            else *addr = hn;
        }
    }
}

__global__ __launch_bounds__(512, 4) void k_main(
    const float* __restrict__ x, const int* __restrict__ bArr, const int* __restrict__ pArr,
    const float* __restrict__ WzT, const float* __restrict__ WrT, const float* __restrict__ WhT,
    const float* __restrict__ UzT, const float* __restrict__ UrT, const float* __restrict__ UhT,
    const float* __restrict__ bz, const float* __restrict__ br, const float* __restrict__ bh,
    float* __restrict__ out,
    const int* __restrict__ order, const int* __restrict__ levelStart,
    const int* __restrict__ numLevels,
    const float* __restrict__ XPz, const float* __restrict__ XPr, const float* __restrict__ XPh,
    int useXP)
{
    cg::grid_group grid = cg::this_grid();
    __shared__ float Hs[16][S2];
    __shared__ float RHs[16][S2];
    __shared__ float xs[16][SIT];
    __shared__ int tj[16];

    const int i = threadIdx.x;
    const float bzi = bz[i], bri = br[i], bhi = bh[i];
    const float4* Uz4 = (const float4*)UzT;
    const float4* Ur4 = (const float4*)UrT;
    const float4* Uh4 = (const float4*)UhT;
    const float4* Wz4 = (const float4*)WzT;
    const float4* Wr4 = (const float4*)WrT;
    const float4* Wh4 = (const float4*)WhT;

    const int nLev = *numLevels;
    const int G = gridDim.x;
    for (int lvl = 1; lvl <= nLev; ++lvl) {
        const int s0 = levelStart[lvl - 1], s1 = levelStart[lvl];
        const int n = s1 - s0;
        if (n <= 4 * G)
            process_level<4>(s0, s1, i, useXP, x, bArr, pArr, Wz4, Wr4, Wh4,
                             Uz4, Ur4, Uh4, XPz, XPr, XPh, bzi, bri, bhi,
                             out, order, Hs, RHs, xs, tj);
        else if (n <= 8 * G)
            process_level<8>(s0, s1, i, useXP, x, bArr, pArr, Wz4, Wr4, Wh4,
                             Uz4, Ur4, Uh4, XPz, XPr, XPh, bzi, bri, bhi,
                             out, order, Hs, RHs, xs, tj);
        else
            process_level<16>(s0, s1, i, useXP, x, bArr, pArr, Wz4, Wr4, Wh4,
                              Uz4, Ur4, Uh4, XPz, XPr, XPh, bzi, bri, bhi,
                              out, order, Hs, RHs, xs, tj);
        grid.sync();
    }
}

// ---------------- host launcher ----------------

extern "C" void kernel_launch(void* const* d_in, const int* in_sizes, int n_in,
                              void* d_out, int out_size, void* d_ws, size_t ws_size,
                              hipStream_t stream) {
    const float* x  = (const float*)d_in[0];
    const int*   b  = (const int*)d_in[1];
    const int*   p  = (const int*)d_in[2];
    const float* Wz = (const float*)d_in[3];
    const float* Wr = (const float*)d_in[4];
    const float* Wh = (const float*)d_in[5];
    const float* Uz = (const float*)d_in[6];
    const float* Ur = (const float*)d_in[7];
    const float* Uh = (const float*)d_in[8];
    const float* bz = (const float*)d_in[9];
    const float* br = (const float*)d_in[10];
    const float* bh = (const float*)d_in[11];
    const float* table0 = (const float*)d_in[12];
    float* out = (float*)d_out;

    float* UzT = (float*)d_ws;
    float* UrT = UzT + S2 * S2;
    float* UhT = UrT + S2 * S2;
    float* WzT = UhT + S2 * S2;
    float* WrT = WzT + S2 * SIT;
    float* WhT = WrT + S2 * SIT;
    int* cnt = (int*)(WhT + S2 * SIT);
    int* cur = cnt + NPL;
    int* bas = cur + NPL;
    int* list = bas + NPL;
    int* pred = list + NEV;
    int* order = pred + NEV;
    int* levelStart = order + T_STEPS;
    int* numLevels = levelStart + 260;

    size_t baseFloats = (size_t)(3 * S2 * S2 + 3 * S2 * SIT) + 3 * NPL + 2 * NEV + T_STEPS + 261;
    baseFloats = (baseFloats + 255) & ~(size_t)255;
    float* XPz = (float*)d_ws + baseFloats;
    float* XPr = XPz + (size_t)T_STEPS * S2;
    float* XPh = XPr + (size_t)T_STEPS * S2;
    size_t needBytes = (baseFloats + 3ull * T_STEPS * S2) * 4ull;
    int useXP = (ws_size >= needBytes) ? 1 : 0;

    hipLaunchKernelGGL(k_trans, dim3(1024, 6), dim3(256), 0, stream,
                       Uz, Ur, Uh, Wz, Wr, Wh, UzT, UrT, UhT, WzT, WrT, WhT);
    hipLaunchKernelGGL(k_zero, dim3((NPL + 255) / 256), dim3(256), 0, stream, cnt);
    hipLaunchKernelGGL(k_count, dim3((NEV + 255) / 256), dim3(256), 0, stream, b, p, cnt);
    hipLaunchKernelGGL(k_scan, dim3(1), dim3(1024), 0, stream, cnt, bas, cur);
    hipLaunchKernelGGL(k_place, dim3((NEV + 255) / 256), dim3(256), 0, stream, b, p, cur, list);
    hipLaunchKernelGGL(k_pred, dim3((NPL + 255) / 256), dim3(256), 0, stream, bas, cnt, list, pred);
    hipLaunchKernelGGL(k_levels, dim3(1), dim3(1024), 0, stream, pred, order, levelStart, numLevels);

    int n4 = NPL * SS / 4;
    hipLaunchKernelGGL(k_copy, dim3((n4 + 255) / 256), dim3(256), 0, stream,
                       (const float4*)table0, (float4*)out, n4);
    if (useXP) {
        hipLaunchKernelGGL(k_xp, dim3(T_STEPS / 16), dim3(512), 0, stream,
                           x, WzT, WrT, WhT, bz, br, bh, XPz, XPr, XPh);
    }

    // grid sizing: query capacity, clamp DOWN only (never exceed what fits)
    int occ = 0;
    if (hipOccupancyMaxActiveBlocksPerMultiprocessor(&occ, k_main, 512, 0) != hipSuccess)
        occ = 1;
    if (occ < 1) occ = 1;
    if (occ > 2) occ = 2;
    int gridSz = occ * 256;

    void* args[] = {
        (void*)&x, (void*)&b, (void*)&p,
        (void*)&WzT, (void*)&WrT, (void*)&WhT,
        (void*)&UzT, (void*)&UrT, (void*)&UhT,
        (void*)&bz, (void*)&br, (void*)&bh,
        (void*)&out,
        (void*)&order, (void*)&levelStart, (void*)&numLevels,
        (void*)&XPz, (void*)&XPr, (void*)&XPh, (void*)&useXP
    };
    hipError_t e = hipLaunchCooperativeKernel((void*)k_main, dim3(gridSz), dim3(512), args, 0, stream);
    if (e != hipSuccess && gridSz != 256) {
        hipLaunchCooperativeKernel((void*)k_main, dim3(256), dim3(512), args, 0, stream);
    }
}

// Round 5
// 1192.806 us; speedup vs baseline: 1.3620x; 1.0855x over previous
//
#include <hip/hip_runtime.h>
#include <hip/hip_cooperative_groups.h>

namespace cg = cooperative_groups;

#define T_STEPS 8192
#define SIT     64
#define SS      256
#define S2      512
#define NPL     32000
#define NEV     (2*T_STEPS)
#define MAXLEV  255
#define RELAX   48
#define NKB     (S2/4)    // 128 k-blocks for U part
#define WKB     (SIT/4)   // 16 k-blocks for W part
#define BQMAX   8

__device__ __forceinline__ float sigmoidf_(float x) {
    return 1.0f / (1.0f + expf(-x));
}
__device__ __forceinline__ float dot4_(float4 a, float4 b) {
    return a.x*b.x + a.y*b.y + a.z*b.z + a.w*b.w;
}

// ---------------- preprocessing kernels ----------------

__global__ void k_zero(int* cnt) {
    int i = blockIdx.x * blockDim.x + threadIdx.x;
    if (i < NPL) cnt[i] = 0;
}

__global__ void k_count(const int* __restrict__ b, const int* __restrict__ p, int* cnt) {
    int e = blockIdx.x * blockDim.x + threadIdx.x;
    if (e < NEV) {
        int v = (e & 1) ? p[e >> 1] : b[e >> 1];
        atomicAdd(&cnt[v], 1);
    }
}

__global__ __launch_bounds__(1024) void k_scan(const int* __restrict__ cnt, int* bas, int* cur) {
    __shared__ int partial[1024];
    int tid = threadIdx.x;
    int start = tid * 32;
    int end = start + 32; if (end > NPL) end = NPL;
    int s = 0;
    for (int i = start; i < end; ++i) s += cnt[i];
    partial[tid] = s;
    __syncthreads();
    for (int off = 1; off < 1024; off <<= 1) {
        int v = partial[tid];
        int add = (tid >= off) ? partial[tid - off] : 0;
        __syncthreads();
        partial[tid] = v + add;
        __syncthreads();
    }
    int acc = (tid == 0) ? 0 : partial[tid - 1];
    for (int i = start; i < end; ++i) {
        bas[i] = acc; cur[i] = acc; acc += cnt[i];
    }
}

__global__ void k_place(const int* __restrict__ b, const int* __restrict__ p, int* cur, int* list) {
    int e = blockIdx.x * blockDim.x + threadIdx.x;
    if (e < NEV) {
        int v = (e & 1) ? p[e >> 1] : b[e >> 1];
        int pos = atomicAdd(&cur[v], 1);
        list[pos] = e;
    }
}

__global__ void k_pred(const int* __restrict__ bas, const int* __restrict__ cnt, int* list, int* pred) {
    int v = blockIdx.x * blockDim.x + threadIdx.x;
    if (v >= NPL) return;
    int s0 = bas[v], c = cnt[v];
    for (int i2 = 1; i2 < c; ++i2) {
        int key = list[s0 + i2];
        int j = i2 - 1;
        while (j >= 0 && list[s0 + j] > key) { list[s0 + j + 1] = list[s0 + j]; --j; }
        list[s0 + j + 1] = key;
    }
    int prevS = -1, curS = -1;
    for (int i2 = 0; i2 < c; ++i2) {
        int e = list[s0 + i2];
        int s = e >> 1;
        if (s != curS) { prevS = curS; curS = s; }
        pred[e] = prevS;
    }
}

__global__ __launch_bounds__(1024) void k_levels(const int* __restrict__ pred,
                                                 int* order, int* levelStart, int* numLevels) {
    __shared__ short p0[T_STEPS], p1[T_STEPS];
    __shared__ unsigned char lev[T_STEPS];
    __shared__ int cnts[MAXLEV + 2];
    __shared__ int maxLev;
    int tid = threadIdx.x;
    for (int t = tid; t < T_STEPS; t += 1024) {
        p0[t] = (short)pred[2 * t];
        p1[t] = (short)pred[2 * t + 1];
        lev[t] = 1;
    }
    for (int l = tid; l < MAXLEV + 2; l += 1024) cnts[l] = 0;
    if (tid == 0) maxLev = 0;
    __syncthreads();
    for (int r = 0; r < RELAX; ++r) {
        for (int t = tid; t < T_STEPS; t += 1024) {
            int a = p0[t], b2 = p1[t];
            int la = (a >= 0) ? (int)lev[a] : 0;
            int lb = (b2 >= 0) ? (int)lev[b2] : 0;
            int nl = 1 + (la > lb ? la : lb);
            if (nl > MAXLEV) nl = MAXLEV;
            if (nl > (int)lev[t]) lev[t] = (unsigned char)nl;
        }
        __syncthreads();
    }
    for (int t = tid; t < T_STEPS; t += 1024) {
        atomicAdd(&cnts[lev[t]], 1);
        atomicMax(&maxLev, (int)lev[t]);
    }
    __syncthreads();
    if (tid == 0) {
        int acc = 0;
        levelStart[0] = 0;
        for (int l = 1; l <= maxLev; ++l) {
            int c = cnts[l];
            cnts[l] = acc;
            acc += c;
            levelStart[l] = acc;
        }
        *numLevels = maxLev;
    }
    __syncthreads();
    for (int t = tid; t < T_STEPS; t += 1024) {
        int pos = atomicAdd(&cnts[lev[t]], 1);
        order[pos] = t;
    }
}

// fused transpose of all 6 matrices into [k/4][512][4] layout
__global__ void k_trans(const float* __restrict__ Uz, const float* __restrict__ Ur,
                        const float* __restrict__ Uh, const float* __restrict__ Wz,
                        const float* __restrict__ Wr, const float* __restrict__ Wh,
                        float* UzT, float* UrT, float* UhT,
                        float* WzT, float* WrT, float* WhT) {
    int y = blockIdx.y;
    int idx = blockIdx.x * blockDim.x + threadIdx.x;
    if (y < 3) {
        const float* S = (y == 0) ? Uz : (y == 1) ? Ur : Uh;
        float*       D = (y == 0) ? UzT : (y == 1) ? UrT : UhT;
        if (idx < S2 * S2) {
            int i2 = idx / S2, k = idx % S2;
            D[((k >> 2) * S2 + i2) * 4 + (k & 3)] = S[idx];
        }
    } else {
        const float* S = (y == 3) ? Wz : (y == 4) ? Wr : Wh;
        float*       D = (y == 3) ? WzT : (y == 4) ? WrT : WhT;
        if (idx < S2 * SIT) {
            int i2 = idx / SIT, k = idx % SIT;
            D[((k >> 2) * S2 + i2) * 4 + (k & 3)] = S[idx];
        }
    }
}

__global__ void k_copy(const float4* __restrict__ src, float4* dst, int n4) {
    int i = blockIdx.x * blockDim.x + threadIdx.x;
    if (i < n4) dst[i] = src[i];
}

// XP = W@x + bias for all steps (non-cooperative; one 16-step tile per block)
__global__ __launch_bounds__(512) void k_xp(
    const float* __restrict__ x,
    const float* __restrict__ WzT, const float* __restrict__ WrT, const float* __restrict__ WhT,
    const float* __restrict__ bz, const float* __restrict__ br, const float* __restrict__ bh,
    float* __restrict__ XPz, float* __restrict__ XPr, float* __restrict__ XPh)
{
    __shared__ float xs[16][SIT];
    const int i = threadIdx.x;
    const int tile = blockIdx.x;              // 0 .. T_STEPS/16-1
    const float4* Wz4 = (const float4*)WzT;
    const float4* Wr4 = (const float4*)WrT;
    const float4* Wh4 = (const float4*)WhT;
    const float bzi = bz[i], bri = br[i], bhi = bh[i];

    for (int idx = i; idx < 16 * SIT; idx += 512) {
        int j = idx >> 6, k = idx & (SIT - 1);
        xs[j][k] = x[(tile * 16 + j) * SIT + k];
    }
    __syncthreads();
    float za[16], ra[16], ha[16];
#pragma unroll
    for (int j = 0; j < 16; ++j) { za[j] = 0.f; ra[j] = 0.f; ha[j] = 0.f; }
    for (int kb = 0; kb < WKB; ++kb) {
        float4 wz = Wz4[kb * S2 + i];
        float4 wr = Wr4[kb * S2 + i];
        float4 wh = Wh4[kb * S2 + i];
#pragma unroll
        for (int j = 0; j < 16; ++j) {
            float4 x4 = *(const float4*)(&xs[j][kb * 4]);
            za[j] += dot4_(wz, x4);
            ra[j] += dot4_(wr, x4);
            ha[j] += dot4_(wh, x4);
        }
    }
#pragma unroll
    for (int j = 0; j < 16; ++j) {
        int t = tile * 16 + j;
        XPz[t * S2 + i] = za[j] + bzi;
        XPr[t * S2 + i] = ra[j] - bri;
        XPh[t * S2 + i] = ha[j] + bhi;
    }
}

// ---------------- main cooperative kernel ----------------

template<int BQ>
__device__ __forceinline__ void process_level(
    int s0, int s1, int i, int useXP,
    const float* __restrict__ x,
    const int* __restrict__ bArr, const int* __restrict__ pArr,
    const float4* __restrict__ Wz4, const float4* __restrict__ Wr4, const float4* __restrict__ Wh4,
    const float4* __restrict__ Uz4, const float4* __restrict__ Ur4, const float4* __restrict__ Uh4,
    const float* __restrict__ XPz, const float* __restrict__ XPr, const float* __restrict__ XPh,
    float bzi, float bri, float bhi,
    float* __restrict__ out, const int* __restrict__ order,
    float (*Hs)[S2], float (*RHs)[S2], float (*xs)[SIT],
    int* tj, int* rbs, int* rps)
{
    const int nT = (s1 - s0 + BQ - 1) / BQ;
    for (int tile = blockIdx.x; tile < nT; tile += gridDim.x) {
        const int sbase = s0 + tile * BQ;
        const int B = (sbase + BQ <= s1) ? BQ : (s1 - sbase);
        __syncthreads();                       // guard LDS reuse from previous tile
        if (i < BQ) {
            int t = (i < B) ? order[sbase + i] : -1;
            tj[i] = t;
            rbs[i] = (t >= 0) ? bArr[t] : 0;
            rps[i] = (t >= 0) ? pArr[t] : 0;
        }
        __syncthreads();

        // gather h = concat(table[b], table[p]) per step
        for (int idx = i; idx < BQ * S2; idx += 512) {
            int j = idx >> 9, k = idx & (S2 - 1);
            float v = 0.0f;
            if (tj[j] >= 0) {
                int row = (k < SS) ? rbs[j] : rps[j];
                v = out[row * SS + (k & (SS - 1))];
            }
            Hs[j][k] = v;
        }
        if (!useXP) {
            for (int idx = i; idx < BQ * SIT; idx += 512) {
                int j = idx >> 6, k = idx & (SIT - 1);
                int t = tj[j];
                xs[j][k] = (t >= 0) ? x[t * SIT + k] : 0.0f;
            }
        }
        // init accumulators (XP holds W@x with biases folded)
        float zacc[BQ], racc[BQ];
        if (useXP) {
#pragma unroll
            for (int j = 0; j < BQ; ++j) {
                int t = tj[j];
                zacc[j] = (t >= 0) ? XPz[t * S2 + i] : 0.0f;
                racc[j] = (t >= 0) ? XPr[t * S2 + i] : 0.0f;
            }
        } else {
#pragma unroll
            for (int j = 0; j < BQ; ++j) { zacc[j] = 0.0f; racc[j] = 0.0f; }
        }
        __syncthreads();                       // Hs (and xs) ready

        if (!useXP) {
            for (int kb = 0; kb < WKB; ++kb) {
                float4 a4 = Wz4[kb * S2 + i];
                float4 b4 = Wr4[kb * S2 + i];
#pragma unroll
                for (int j = 0; j < BQ; ++j) {
                    float4 x4 = *(const float4*)(&xs[j][kb * 4]);
                    zacc[j] += dot4_(a4, x4);
                    racc[j] += dot4_(b4, x4);
                }
            }
        }
        // U z/r loop, 2-deep software prefetch
        {
            float4 az0 = Uz4[i],       ar0 = Ur4[i];
            float4 az1 = Uz4[S2 + i],  ar1 = Ur4[S2 + i];
#pragma unroll 1
            for (int kb = 0; kb < NKB; ++kb) {
                float4 azc = az0, arc = ar0;
                az0 = az1; ar0 = ar1;
                int kn = kb + 2; if (kn >= NKB) kn -= NKB;
                az1 = Uz4[kn * S2 + i];
                ar1 = Ur4[kn * S2 + i];
#pragma unroll
                for (int j = 0; j < BQ; ++j) {
                    float4 h4 = *(const float4*)(&Hs[j][kb * 4]);
                    zacc[j] += dot4_(azc, h4);
                    racc[j] += dot4_(arc, h4);
                }
            }
        }
        float zv[BQ];
#pragma unroll
        for (int j = 0; j < BQ; ++j) {
            zv[j] = sigmoidf_(useXP ? zacc[j] : (zacc[j] + bzi));
            float rv = sigmoidf_(useXP ? racc[j] : (racc[j] - bri));
            RHs[j][i] = rv * Hs[j][i];
        }
        __syncthreads();                       // RHs ready

        // phase B: m
        float macc[BQ];
        if (useXP) {
#pragma unroll
            for (int j = 0; j < BQ; ++j) {
                int t = tj[j];
                macc[j] = (t >= 0) ? XPh[t * S2 + i] : 0.0f;
            }
        } else {
#pragma unroll
            for (int j = 0; j < BQ; ++j) macc[j] = 0.0f;
            for (int kb = 0; kb < WKB; ++kb) {
                float4 a4 = Wh4[kb * S2 + i];
#pragma unroll
                for (int j = 0; j < BQ; ++j) {
                    float4 x4 = *(const float4*)(&xs[j][kb * 4]);
                    macc[j] += dot4_(a4, x4);
                }
            }
        }
        {
            float4 ah0 = Uh4[i];
            float4 ah1 = Uh4[S2 + i];
#pragma unroll 1
            for (int kb = 0; kb < NKB; ++kb) {
                float4 ahc = ah0;
                ah0 = ah1;
                int kn = kb + 2; if (kn >= NKB) kn -= NKB;
                ah1 = Uh4[kn * S2 + i];
#pragma unroll
                for (int j = 0; j < BQ; ++j) {
                    float4 h4 = *(const float4*)(&RHs[j][kb * 4]);
                    macc[j] += dot4_(ahc, h4);
                }
            }
        }
        // scatter
        for (int j = 0; j < B; ++j) {
            float mm = tanhf(useXP ? macc[j] : (macc[j] + bhi));
            float h = Hs[j][i];
            float hn = zv[j] * h + (1.0f - zv[j]) * mm;
            int rb = rbs[j], rp = rps[j];
            int row = (i < SS) ? rb : rp;
            float* addr = out + row * SS + (i & (SS - 1));
            if (rb == rp) atomicAdd(addr, hn - h);
            else *addr = hn;
        }
    }
}

__global__ __launch_bounds__(512, 6) void k_main(
    const float* __restrict__ x, const int* __restrict__ bArr, const int* __restrict__ pArr,
    const float* __restrict__ WzT, const float* __restrict__ WrT, const float* __restrict__ WhT,
    const float* __restrict__ UzT, const float* __restrict__ UrT, const float* __restrict__ UhT,
    const float* __restrict__ bz, const float* __restrict__ br, const float* __restrict__ bh,
    float* __restrict__ out,
    const int* __restrict__ order, const int* __restrict__ levelStart,
    const int* __restrict__ numLevels,
    const float* __restrict__ XPz, const float* __restrict__ XPr, const float* __restrict__ XPh,
    int useXP)
{
    cg::grid_group grid = cg::this_grid();
    __shared__ float Hs[BQMAX][S2];
    __shared__ float RHs[BQMAX][S2];
    __shared__ float xs[BQMAX][SIT];
    __shared__ int tj[BQMAX], rbs[BQMAX], rps[BQMAX];

    const int i = threadIdx.x;
    const float bzi = bz[i], bri = br[i], bhi = bh[i];
    const float4* Uz4 = (const float4*)UzT;
    const float4* Ur4 = (const float4*)UrT;
    const float4* Uh4 = (const float4*)UhT;
    const float4* Wz4 = (const float4*)WzT;
    const float4* Wr4 = (const float4*)WrT;
    const float4* Wh4 = (const float4*)WhT;

    const int nLev = *numLevels;
    for (int lvl = 1; lvl <= nLev; ++lvl) {
        const int s0 = levelStart[lvl - 1], s1 = levelStart[lvl];
        const int n = s1 - s0;
        // per-level BQ minimizing max(VALU ~2.56*BQ us, L2 ~0.087*n/BQ us)
        if (n > 1200)
            process_level<8>(s0, s1, i, useXP, x, bArr, pArr, Wz4, Wr4, Wh4,
                             Uz4, Ur4, Uh4, XPz, XPr, XPh, bzi, bri, bhi,
                             out, order, Hs, RHs, xs, tj, rbs, rps);
        else if (n > 300)
            process_level<4>(s0, s1, i, useXP, x, bArr, pArr, Wz4, Wr4, Wh4,
                             Uz4, Ur4, Uh4, XPz, XPr, XPh, bzi, bri, bhi,
                             out, order, Hs, RHs, xs, tj, rbs, rps);
        else
            process_level<2>(s0, s1, i, useXP, x, bArr, pArr, Wz4, Wr4, Wh4,
                             Uz4, Ur4, Uh4, XPz, XPr, XPh, bzi, bri, bhi,
                             out, order, Hs, RHs, xs, tj, rbs, rps);
        grid.sync();
    }
}

// ---------------- host launcher ----------------

extern "C" void kernel_launch(void* const* d_in, const int* in_sizes, int n_in,
                              void* d_out, int out_size, void* d_ws, size_t ws_size,
                              hipStream_t stream) {
    const float* x  = (const float*)d_in[0];
    const int*   b  = (const int*)d_in[1];
    const int*   p  = (const int*)d_in[2];
    const float* Wz = (const float*)d_in[3];
    const float* Wr = (const float*)d_in[4];
    const float* Wh = (const float*)d_in[5];
    const float* Uz = (const float*)d_in[6];
    const float* Ur = (const float*)d_in[7];
    const float* Uh = (const float*)d_in[8];
    const float* bz = (const float*)d_in[9];
    const float* br = (const float*)d_in[10];
    const float* bh = (const float*)d_in[11];
    const float* table0 = (const float*)d_in[12];
    float* out = (float*)d_out;

    float* UzT = (float*)d_ws;
    float* UrT = UzT + S2 * S2;
    float* UhT = UrT + S2 * S2;
    float* WzT = UhT + S2 * S2;
    float* WrT = WzT + S2 * SIT;
    float* WhT = WrT + S2 * SIT;
    int* cnt = (int*)(WhT + S2 * SIT);
    int* cur = cnt + NPL;
    int* bas = cur + NPL;
    int* list = bas + NPL;
    int* pred = list + NEV;
    int* order = pred + NEV;
    int* levelStart = order + T_STEPS;
    int* numLevels = levelStart + 260;

    size_t baseFloats = (size_t)(3 * S2 * S2 + 3 * S2 * SIT) + 3 * NPL + 2 * NEV + T_STEPS + 261;
    baseFloats = (baseFloats + 255) & ~(size_t)255;
    float* XPz = (float*)d_ws + baseFloats;
    float* XPr = XPz + (size_t)T_STEPS * S2;
    float* XPh = XPr + (size_t)T_STEPS * S2;
    size_t needBytes = (baseFloats + 3ull * T_STEPS * S2) * 4ull;
    int useXP = (ws_size >= needBytes) ? 1 : 0;

    hipLaunchKernelGGL(k_trans, dim3(1024, 6), dim3(256), 0, stream,
                       Uz, Ur, Uh, Wz, Wr, Wh, UzT, UrT, UhT, WzT, WrT, WhT);
    hipLaunchKernelGGL(k_zero, dim3((NPL + 255) / 256), dim3(256), 0, stream, cnt);
    hipLaunchKernelGGL(k_count, dim3((NEV + 255) / 256), dim3(256), 0, stream, b, p, cnt);
    hipLaunchKernelGGL(k_scan, dim3(1), dim3(1024), 0, stream, cnt, bas, cur);
    hipLaunchKernelGGL(k_place, dim3((NEV + 255) / 256), dim3(256), 0, stream, b, p, cur, list);
    hipLaunchKernelGGL(k_pred, dim3((NPL + 255) / 256), dim3(256), 0, stream, bas, cnt, list, pred);
    hipLaunchKernelGGL(k_levels, dim3(1), dim3(1024), 0, stream, pred, order, levelStart, numLevels);

    int n4 = NPL * SS / 4;
    hipLaunchKernelGGL(k_copy, dim3((n4 + 255) / 256), dim3(256), 0, stream,
                       (const float4*)table0, (float4*)out, n4);
    if (useXP) {
        hipLaunchKernelGGL(k_xp, dim3(T_STEPS / 16), dim3(512), 0, stream,
                           x, WzT, WrT, WhT, bz, br, bh, XPz, XPr, XPh);
    }

    // grid sizing: query capacity, clamp DOWN only (never exceed what fits)
    int occ = 0;
    if (hipOccupancyMaxActiveBlocksPerMultiprocessor(&occ, k_main, 512, 0) != hipSuccess)
        occ = 1;
    if (occ < 1) occ = 1;
    if (occ > 4) occ = 4;
    int gridSz = occ * 256;

    void* args[] = {
        (void*)&x, (void*)&b, (void*)&p,
        (void*)&WzT, (void*)&WrT, (void*)&WhT,
        (void*)&UzT, (void*)&UrT, (void*)&UhT,
        (void*)&bz, (void*)&br, (void*)&bh,
        (void*)&out,
        (void*)&order, (void*)&levelStart, (void*)&numLevels,
        (void*)&XPz, (void*)&XPr, (void*)&XPh, (void*)&useXP
    };
    hipError_t e = hipLaunchCooperativeKernel((void*)k_main, dim3(gridSz), dim3(512), args, 0, stream);
    if (e != hipSuccess && gridSz != 256) {
        hipLaunchCooperativeKernel((void*)k_main, dim3(256), dim3(512), args, 0, stream);
    }
}